// Round 6
// baseline (782.646 us; speedup 1.0000x reference)
//
#include <hip/hip_runtime.h>
#include <hip/hip_bf16.h>
#include <math.h>

#define B_SIZE 16384
#define J_ENS  10

// ---- workspace layout ----
// u16-unit offsets (bf16 regions)
#define U_WB1   0           // [512][256] bf16  gate weights [N][K]
#define U_WB2   131072      // [128][128] bf16  fc2 [N][K] (k>=120 zero)
#define U_WB3   147456      // [32][128]  bf16  fc3 [N][K]
#define U_A1S   152576      // [B][120]   bf16  pre-scaled a1 (relu*i1)
// float-unit offsets
#define F_GB    75776       // [4][128] f32 combined gate biases
#define F_XPRED 1059328     // [B][8]  f32
#define F_INNOV 1190400     // [B][4]  f32
#define F_CORR  1255936     // [J*B][8] f32

typedef __attribute__((ext_vector_type(8))) short s16x8;
typedef __attribute__((ext_vector_type(4))) float f32x4;

__device__ __forceinline__ float sigm(float x) { return 1.f / (1.f + expf(-x)); }
__device__ __forceinline__ float fsigm(float x) { return __builtin_amdgcn_rcpf(1.f + __expf(-x)); }
__device__ __forceinline__ float ftanh(float x) {
    float e = __expf(2.f * x);
    return 1.f - 2.f * __builtin_amdgcn_rcpf(e + 1.f);
}
__device__ __forceinline__ unsigned short f2bf(float x) {
    __hip_bfloat16 h = __float2bfloat16(x);
    return __builtin_bit_cast(unsigned short, h);
}

// ---------------- prep: weights -> bf16 [N][K] padded + gate biases (+ reg scalar in last block) ----------------
__global__ void prep_kernel(const float* __restrict__ Wih, const float* __restrict__ Whh,
                            const float* __restrict__ bih, const float* __restrict__ bhh,
                            const float* __restrict__ Wfc2, const float* __restrict__ Wfc3,
                            const float* __restrict__ W1, const float* __restrict__ pl1,
                            const float* __restrict__ pl2, float* __restrict__ out,
                            float* __restrict__ ws) {
    if (blockIdx.x == 594) {
        // ---- regularizer scalar (merged reg_kernel) ----
        __shared__ float red[256];
        int t = threadIdx.x;
        float s1 = 0.f, s2 = 0.f;
        for (int i = t; i < 1440; i += 256)  { float v = W1[i];  s1 = fmaf(v, v, s1); }
        for (int i = t; i < 15360; i += 256) { float v = Wfc2[i]; s2 = fmaf(v, v, s2); }
        red[t] = s1; __syncthreads();
        for (int s = 128; s > 0; s >>= 1) { if (t < s) red[t] += red[t + s]; __syncthreads(); }
        float r1 = red[0]; __syncthreads();
        red[t] = s2; __syncthreads();
        for (int s = 128; s > 0; s >>= 1) { if (t < s) red[t] += red[t + s]; __syncthreads(); }
        if (t == 0) {
            float p1 = sigm(pl1[0]), p2 = sigm(pl2[0]);
            float e1 = p1 * logf(p1) + (1.f - p1) * logf(1.f - p1);
            float e2 = p2 * logf(p2) + (1.f - p2) * logf(1.f - p2);
            out[1179648] = r1 / (1.f - p1) + e1 + red[0] / (1.f - p2) + e2;
        }
        return;
    }
    unsigned short* wsu = (unsigned short*)ws;
    int idx = blockIdx.x * 256 + threadIdx.x;
    if (idx < 131072) {                     // WB1 [n=512][k=256]
        int n = idx >> 8, k = idx & 255;
        int cb = n >> 7, nn = n & 127;
        float v = 0.f;
        if (nn < 120) {
            if (cb == 0)      v = (k < 120) ? Wih[nn * 120 + k]         : ((k < 240) ? Whh[nn * 120 + (k - 120)] : 0.f);
            else if (cb == 1) v = (k < 120) ? Wih[(120 + nn) * 120 + k] : ((k < 240) ? Whh[(120 + nn) * 120 + (k - 120)] : 0.f);
            else if (cb == 2) v = (k < 120) ? Wih[(240 + nn) * 120 + k] : 0.f;
            else              v = (k >= 120 && k < 240) ? Whh[(240 + nn) * 120 + (k - 120)] : 0.f;
        }
        wsu[U_WB1 + idx] = f2bf(v);
    } else if (idx < 147456) {              // WB2 [o=128][k=128]
        int i2 = idx - 131072; int o = i2 >> 7, k = i2 & 127;
        wsu[U_WB2 + i2] = f2bf((k < 120) ? Wfc2[o * 120 + k] : 0.f);
    } else if (idx < 151552) {              // WB3 [v=32][k=128] (exact copy)
        int i3 = idx - 147456;
        wsu[U_WB3 + i3] = f2bf(Wfc3[i3]);
    } else if (idx < 152064) {              // gate biases [4][128] f32
        int i4 = idx - 151552; int g = i4 >> 7, n = i4 & 127;
        float v = 0.f;
        if (n < 120) {
            if (g == 0)      v = bih[n] + bhh[n];
            else if (g == 1) v = bih[120 + n] + bhh[120 + n];
            else if (g == 2) v = bih[240 + n];
            else             v = bhh[240 + n];
        }
        ws[F_GB + i4] = v;
    }
}

// ---------------- per-b precompute: 256 blocks x 64 b's; a1 computed by all 256 threads ----------------
__global__ void pre_kernel(const float* __restrict__ y_t, const float* __restrict__ xprev,
                           const float* __restrict__ dxprev, const float* __restrict__ F,
                           const float* __restrict__ Hm, const float* __restrict__ W1,
                           const float* __restrict__ b1, const float* __restrict__ pl1,
                           float* __restrict__ ws) {
    __shared__ float nnl[64][12];
    __shared__ float W1l[1440];
    __shared__ float b1l[120];
    unsigned short* wsu = (unsigned short*)ws;
    const int t  = threadIdx.x;
    const int b0 = blockIdx.x * 64;
    const float p1 = sigm(pl1[0]);
    const float i1 = 1.f / (1.f - p1);

    for (int i = t; i < 1440; i += 256) W1l[i] = W1[i];
    if (t < 120) b1l[t] = b1[t];

    if (t < 64) {
        int b = b0 + t;
        float xf[8], dx[8], xp[8];
#pragma unroll
        for (int s = 0; s < 8; ++s) { xf[s] = xprev[b * 8 + s]; dx[s] = dxprev[b * 8 + s]; }
#pragma unroll
        for (int s = 0; s < 8; ++s) {
            float a = 0.f;
#pragma unroll
            for (int q = 0; q < 8; ++q) a = fmaf(F[s * 8 + q], xf[q], a);
            xp[s] = a;
        }
        float inn[4];
#pragma unroll
        for (int o = 0; o < 4; ++o) {
            float a = 0.f;
#pragma unroll
            for (int s = 0; s < 8; ++s) a = fmaf(Hm[o * 8 + s], xp[s], a);
            inn[o] = y_t[b * 4 + o] - a;
        }
        float nd = 0.f, ni = 0.f;
#pragma unroll
        for (int s = 0; s < 8; ++s) nd = fmaf(dx[s], dx[s], nd);
#pragma unroll
        for (int o = 0; o < 4; ++o) ni = fmaf(inn[o], inn[o], ni);
        nd = fmaxf(sqrtf(nd), 1e-12f);
        ni = fmaxf(sqrtf(ni), 1e-12f);
#pragma unroll
        for (int s = 0; s < 8; ++s) nnl[t][s] = dx[s] / nd;
#pragma unroll
        for (int o = 0; o < 4; ++o) nnl[t][8 + o] = inn[o] / ni;
#pragma unroll
        for (int s = 0; s < 8; ++s) ws[F_XPRED + b * 8 + s] = xp[s];
#pragma unroll
        for (int o = 0; o < 4; ++o) ws[F_INNOV + b * 4 + o] = inn[o];
    }
    __syncthreads();

    // a1: 64*120 = 7680 outputs, coalesced bf16 stores
    for (int idx = t; idx < 7680; idx += 256) {
        int m = idx / 120, n = idx % 120;
        float a = b1l[n];
#pragma unroll
        for (int i = 0; i < 12; ++i) a = fmaf(W1l[n * 12 + i], nnl[m][i], a);
        wsu[U_A1S + (size_t)(b0 + m) * 120 + n] = f2bf(fmaxf(a, 0.f) * i1);
    }
}

// ---------------- main fused MFMA kernel: 64 rows per block, 8 waves (512 thr), LDS-overlaid ----------------
// LDS timeline (all transitions barrier-separated):
//   [0,33792)      Xl [64][264] bf16   (stage + phase-1 gemm)
//   [0,17408)      A2l [64][136] bf16  (phase-2 epilogue .. phase-3 gemm)   — overlays dead Xl
//   [17408,27648)  Kvl [64][40] f32    (phase-3 epilogue .. corr)           — overlays dead Xl
//   [33792,51200)  Hn [64][136] bf16   (phase-1 epilogue .. phase-2 gemm)
__launch_bounds__(512, 6)
__global__ void main_kernel(const float* __restrict__ hprev, const float* __restrict__ u1,
                            const float* __restrict__ u2, const float* __restrict__ b2,
                            const float* __restrict__ b3, const float* __restrict__ pl1,
                            const float* __restrict__ pl2, float* __restrict__ ws) {
    __shared__ unsigned char smem[51200];
    unsigned short* Xl  = (unsigned short*)smem;             // [64][264]
    unsigned short* A2l = (unsigned short*)smem;             // [64][136]
    float*          Kvl = (float*)(smem + 17408);            // [64][40]
    unsigned short* Hn  = (unsigned short*)(smem + 33792);   // [64][136]

    const unsigned short* WB1p = (const unsigned short*)ws + U_WB1;
    const unsigned short* WB2p = (const unsigned short*)ws + U_WB2;
    const unsigned short* WB3p = (const unsigned short*)ws + U_WB3;
    const unsigned short* a1s  = (const unsigned short*)ws + U_A1S;
    const float* GB = ws + F_GB;

    const int t  = threadIdx.x;
    const int r0 = blockIdx.x * 64;
    const int b0 = r0 & (B_SIZE - 1);

    const float p1 = sigm(pl1[0]);
    const float p2 = sigm(pl2[0]);
    const float i2 = 1.f / (1.f - p2);

    // ---- stage X = [a1_masked | h_prev] as bf16 ----
    for (int idx = t; idx < 1920; idx += 512) {
        int m = idx / 30, q = (idx % 30) * 4;
        float4 uu = *(const float4*)&u1[(size_t)(r0 + m) * 120 + q];
        ushort4 aa = *(const ushort4*)&a1s[(b0 + m) * 120 + q];
        ushort4 xv;
        xv.x = (uu.x >= p1) ? aa.x : (unsigned short)0;
        xv.y = (uu.y >= p1) ? aa.y : (unsigned short)0;
        xv.z = (uu.z >= p1) ? aa.z : (unsigned short)0;
        xv.w = (uu.w >= p1) ? aa.w : (unsigned short)0;
        *(ushort4*)&Xl[m * 264 + q] = xv;
        float4 hh = *(const float4*)&hprev[(size_t)(r0 + m) * 120 + q];
        ushort4 hv;
        hv.x = f2bf(hh.x); hv.y = f2bf(hh.y); hv.z = f2bf(hh.z); hv.w = f2bf(hh.w);
        *(ushort4*)&Xl[m * 264 + 120 + q] = hv;
    }
    // zero pad Xl cols 240..255 (one ushort2 per thread)
    {
        int m = t >> 3, c = 240 + ((t & 7) << 1);
        ushort2 z; z.x = 0; z.y = 0;
        *(ushort2*)&Xl[m * 264 + c] = z;
    }
    // zero pad Hn cols 120..127
    if (t < 256) {
        int m = t >> 2, c = 120 + ((t & 3) << 1);
        ushort2 z; z.x = 0; z.y = 0;
        *(ushort2*)&Hn[m * 136 + c] = z;
    }
    __syncthreads();

    const int wv = t >> 6;          // wave 0..7
    const int ln = t & 63;
    const int lr = ln & 15;         // A-row / B-col within frag
    const int kg = (ln >> 4) * 8;   // k-offset within frag
    const int rbase = (ln >> 4) * 4;

    // ---- phase 1: gates GEMM [64x256]x[256x512]; wave wv owns cols wv*16..wv*16+15 of each gate ----
    f32x4 acc[16];
#pragma unroll
    for (int i = 0; i < 16; ++i) acc[i] = (f32x4){0.f, 0.f, 0.f, 0.f};
#pragma unroll
    for (int ks = 0; ks < 8; ++ks) {
        s16x8 af[4];
#pragma unroll
        for (int mf = 0; mf < 4; ++mf)
            af[mf] = *(const s16x8*)&Xl[(mf * 16 + lr) * 264 + ks * 32 + kg];
#pragma unroll
        for (int g = 0; g < 4; ++g) {
            s16x8 bf = *(const s16x8*)&WB1p[(size_t)(g * 128 + wv * 16 + lr) * 256 + ks * 32 + kg];
#pragma unroll
            for (int mf = 0; mf < 4; ++mf)
                acc[mf * 4 + g] =
                    __builtin_amdgcn_mfma_f32_16x16x32_bf16(af[mf], bf, acc[mf * 4 + g], 0, 0, 0);
        }
    }

    // ---- GRU nonlinearity epilogue -> Hn (bf16) ----
    {
        int c = wv * 16 + lr;
        if (c < 120) {
            float br = GB[c], bz = GB[128 + c], bx = GB[256 + c], bg = GB[384 + c];
#pragma unroll
            for (int mf = 0; mf < 4; ++mf) {
                f32x4 rA = acc[mf * 4 + 0];
                f32x4 zA = acc[mf * 4 + 1];
                f32x4 xA = acc[mf * 4 + 2];
                f32x4 gA = acc[mf * 4 + 3];
#pragma unroll
                for (int rr = 0; rr < 4; ++rr) {
                    int row = mf * 16 + rbase + rr;
                    float hp = hprev[(size_t)(r0 + row) * 120 + c];
                    float r = fsigm(rA[rr] + br);
                    float z = fsigm(zA[rr] + bz);
                    float n = ftanh(xA[rr] + bx + r * (gA[rr] + bg));
                    Hn[row * 136 + c] = f2bf((1.f - z) * n + z * hp);
                }
            }
        }
    }
    __syncthreads();   // Hn visible; Xl dead from here (A2l/Kvl may overlay)

    // ---- phase 2: fc2 [64x128]x[128x128] + relu + dropout -> A2l; wave wv owns cols wv*16.. ----
    f32x4 acc2[4];
#pragma unroll
    for (int i = 0; i < 4; ++i) acc2[i] = (f32x4){0.f, 0.f, 0.f, 0.f};
#pragma unroll
    for (int ks = 0; ks < 4; ++ks) {
        s16x8 af[4];
#pragma unroll
        for (int mf = 0; mf < 4; ++mf)
            af[mf] = *(const s16x8*)&Hn[(mf * 16 + lr) * 136 + ks * 32 + kg];
        s16x8 bf = *(const s16x8*)&WB2p[(wv * 16 + lr) * 128 + ks * 32 + kg];
#pragma unroll
        for (int mf = 0; mf < 4; ++mf)
            acc2[mf] = __builtin_amdgcn_mfma_f32_16x16x32_bf16(af[mf], bf, acc2[mf], 0, 0, 0);
    }
    {
        int c = wv * 16 + lr;
        float bb = b2[c];
#pragma unroll
        for (int mf = 0; mf < 4; ++mf) {
#pragma unroll
            for (int rr = 0; rr < 4; ++rr) {
                int row = mf * 16 + rbase + rr;
                float uu = u2[(size_t)(r0 + row) * 128 + c];
                float v = fmaxf(acc2[mf][rr] + bb, 0.f);
                v = (uu >= p2) ? v * i2 : 0.f;
                A2l[row * 136 + c] = f2bf(v);
            }
        }
    }
    __syncthreads();   // A2l visible (Hn dead)

    // ---- phase 3: fc3 [64x128]x[128x32] -> Kvl; wave = (rows (wv&3)*16, cols (wv>>2)*16) ----
    {
        const int m0 = (wv & 3) * 16;
        const int cg = (wv >> 2) * 16;
        f32x4 a3 = (f32x4){0.f, 0.f, 0.f, 0.f};
#pragma unroll
        for (int ks = 0; ks < 4; ++ks) {
            s16x8 a = *(const s16x8*)&A2l[(m0 + lr) * 136 + ks * 32 + kg];
            s16x8 bf = *(const s16x8*)&WB3p[(cg + lr) * 128 + ks * 32 + kg];
            a3 = __builtin_amdgcn_mfma_f32_16x16x32_bf16(a, bf, a3, 0, 0, 0);
        }
        int c = cg + lr;
        float bb = b3[c];
#pragma unroll
        for (int rr = 0; rr < 4; ++rr) {
            int row = m0 + rbase + rr;
            Kvl[row * 40 + c] = a3[rr] + bb;
        }
    }
    __syncthreads();

    // ---- corr = K . innovation (one output per thread) ----
    {
        int m = t >> 3, s = t & 7;
        float4 iv = *(const float4*)&ws[F_INNOV + (b0 + m) * 4];
        const float* kv = &Kvl[m * 40 + s * 4];
        ws[F_CORR + (size_t)(r0 + m) * 8 + s] =
            fmaf(kv[3], iv.w, fmaf(kv[2], iv.z, fmaf(kv[1], iv.y, kv[0] * iv.x)));
    }
}

// ---------------- per-b reduction over J: 256 blocks x 64 threads ----------------
__global__ void reduce_kernel(const float* __restrict__ ws, float* __restrict__ out) {
    int b = blockIdx.x * 64 + threadIdx.x;
    if (b >= B_SIZE) return;
    const float* corr  = ws + F_CORR;
    const float* xpred = ws + F_XPRED;
    float S[8];
    float SS[64];
#pragma unroll
    for (int s = 0; s < 8; ++s) S[s] = 0.f;
#pragma unroll
    for (int q = 0; q < 64; ++q) SS[q] = 0.f;
    for (int j = 0; j < J_ENS; ++j) {
        float c[8];
        float4 c0 = *(const float4*)&corr[(size_t)(j * B_SIZE + b) * 8];
        float4 c1 = *(const float4*)&corr[(size_t)(j * B_SIZE + b) * 8 + 4];
        c[0] = c0.x; c[1] = c0.y; c[2] = c0.z; c[3] = c0.w;
        c[4] = c1.x; c[5] = c1.y; c[6] = c1.z; c[7] = c1.w;
#pragma unroll
        for (int s = 0; s < 8; ++s) S[s] += c[s];
#pragma unroll
        for (int s = 0; s < 8; ++s)
#pragma unroll
            for (int tt = 0; tt < 8; ++tt) SS[s * 8 + tt] = fmaf(c[s], c[tt], SS[s * 8 + tt]);
    }
    const float invJ = 1.f / (float)J_ENS;
    float mc[8];
#pragma unroll
    for (int s = 0; s < 8; ++s) {
        mc[s] = S[s] * invJ;
        out[b * 8 + s] = xpred[b * 8 + s] + mc[s];
    }
#pragma unroll
    for (int s = 0; s < 8; ++s)
#pragma unroll
        for (int tt = 0; tt < 8; ++tt)
            out[131072 + b * 64 + s * 8 + tt] = SS[s * 8 + tt] * invJ - mc[s] * mc[tt];
}

extern "C" void kernel_launch(void* const* d_in, const int* in_sizes, int n_in,
                              void* d_out, int out_size, void* d_ws, size_t ws_size,
                              hipStream_t stream) {
    const float* y_t   = (const float*)d_in[0];
    const float* xfp   = (const float*)d_in[1];
    const float* dxp   = (const float*)d_in[2];
    const float* hprev = (const float*)d_in[3];
    const float* F     = (const float*)d_in[4];
    const float* Hm    = (const float*)d_in[5];
    const float* W1    = (const float*)d_in[6];
    const float* b1    = (const float*)d_in[7];
    const float* Wih   = (const float*)d_in[8];
    const float* Whh   = (const float*)d_in[9];
    const float* bih   = (const float*)d_in[10];
    const float* bhh   = (const float*)d_in[11];
    const float* W2    = (const float*)d_in[12];
    const float* b2    = (const float*)d_in[13];
    const float* W3    = (const float*)d_in[14];
    const float* b3    = (const float*)d_in[15];
    const float* pl1   = (const float*)d_in[16];
    const float* pl2   = (const float*)d_in[17];
    const float* u1    = (const float*)d_in[18];
    const float* u2    = (const float*)d_in[19];
    float* out = (float*)d_out;
    float* ws  = (float*)d_ws;

    prep_kernel<<<dim3(595), dim3(256), 0, stream>>>(Wih, Whh, bih, bhh, W2, W3, W1, pl1, pl2, out, ws);
    pre_kernel<<<dim3(256), dim3(256), 0, stream>>>(y_t, xfp, dxp, F, Hm, W1, b1, pl1, ws);
    main_kernel<<<dim3(2560), dim3(512), 0, stream>>>(hprev, u1, u2, b2, b3, pl1, pl2, ws);
    reduce_kernel<<<dim3(256), dim3(64), 0, stream>>>(ws, out);
}